// Round 1
// baseline (195.127 us; speedup 1.0000x reference)
//
#include <hip/hip_runtime.h>
#include <hip/hip_bf16.h>

// Problem constants: x is [16, 256, 128, 128] float32.
#define B 16
#define C 256
#define H 128
#define W 128
#define HW (H * W)            // 16384
#define BC (B * C)            // 4096
#define KSEL 26               // round(0.1 * 256)

// -------------------- Kernel 1: per-channel score --------------------
// One block (256 threads) per (b,c). Each thread handles 16 float4 = 64 elems.
// Histogram kept in registers (fully unrolled, static indexing), sums in double.
__global__ __launch_bounds__(256) void score_kernel(const float* __restrict__ x,
                                                    double* __restrict__ score) {
    const int bc = blockIdx.x;
    const float4* xv = (const float4*)(x + (size_t)bc * HW);

    int cnt[11];
#pragma unroll
    for (int k = 0; k < 11; ++k) cnt[k] = 0;
    double sum = 0.0, sumsq = 0.0;

    for (int i = threadIdx.x; i < HW / 4; i += 256) {
        float4 v = xv[i];
        float vv[4] = {v.x, v.y, v.z, v.w};
#pragma unroll
        for (int j = 0; j < 4; ++j) {
            float f = vv[j];
            sum += (double)f;
            sumsq += (double)f * (double)f;
            // mimic numpy float32 pipeline: round-half-even of tanh(x)*10
            float q = rintf(tanhf(f) * 10.0f);
            bool ok = (q >= 0.0f) && (q <= 10.0f);
            int bin = (int)q;
#pragma unroll
            for (int k = 0; k < 11; ++k) cnt[k] += (ok && (bin == k)) ? 1 : 0;
        }
    }

    // wave(64)-level reduction
#pragma unroll
    for (int off = 32; off > 0; off >>= 1) {
#pragma unroll
        for (int k = 0; k < 11; ++k) cnt[k] += __shfl_down(cnt[k], off);
        sum += __shfl_down(sum, off);
        sumsq += __shfl_down(sumsq, off);
    }

    __shared__ int sh_cnt[4][11];
    __shared__ double sh_sum[4], sh_sq[4];
    const int wave = threadIdx.x >> 6;
    const int lane = threadIdx.x & 63;
    if (lane == 0) {
#pragma unroll
        for (int k = 0; k < 11; ++k) sh_cnt[wave][k] = cnt[k];
        sh_sum[wave] = sum;
        sh_sq[wave] = sumsq;
    }
    __syncthreads();

    if (threadIdx.x == 0) {
        int c[11];
        int tot = 0;
#pragma unroll
        for (int k = 0; k < 11; ++k) {
            c[k] = sh_cnt[0][k] + sh_cnt[1][k] + sh_cnt[2][k] + sh_cnt[3][k];
            tot += c[k];
        }
        double s = sh_sum[0] + sh_sum[1] + sh_sum[2] + sh_sum[3];
        double sq = sh_sq[0] + sh_sq[1] + sh_sq[2] + sh_sq[3];

        double ent = 0.0;
        double inv = 1.0 / (double)tot;
#pragma unroll
        for (int k = 0; k < 11; ++k) {
            double p = (double)c[k] * inv;
            if (p > 0.0) ent -= p * log(p);
        }
        const double L = (double)HW;
        double var = (sq - s * s / L) / (L - 1.0);
        score[bc] = ent + 2.0 / (var + 1e-7);
    }
}

// -------------------- Kernel 2: top-k selection per batch --------------------
// One block per batch; rank-by-counting with stable-argsort tie semantics
// (ties broken toward lower channel index, matching jnp.argsort stability).
__global__ __launch_bounds__(256) void select_kernel(const double* __restrict__ score,
                                                     unsigned char* __restrict__ sel) {
    __shared__ double s[C];
    const int b = blockIdx.x;
    const int t = threadIdx.x;
    s[t] = score[b * C + t];
    __syncthreads();
    const double mine = s[t];
    int rank = 0;
    for (int j = 0; j < C; ++j) {
        double v = s[j];
        rank += (v > mine) || (v == mine && j < t);
    }
    sel[b * C + t] = (rank < KSEL) ? 1 : 0;
}

// -------------------- Kernel 3: apply Laplace or copy --------------------
// Each block handles 8 rows of one channel. Uniform branch per block on sel.
#define ROWS 8
__global__ __launch_bounds__(256) void apply_kernel(const float* __restrict__ x,
                                                    const unsigned char* __restrict__ sel,
                                                    float* __restrict__ out) {
    const int chunk = blockIdx.x & (H / ROWS - 1);  // 16 chunks per channel
    const int bc = blockIdx.x >> 4;
    const int h0 = chunk * ROWS;
    const float* xc = x + (size_t)bc * HW;
    float* oc = out + (size_t)bc * HW;

    if (!sel[bc]) {
        // pure copy: 8 rows = 1024 floats = 256 float4 (one per thread)
        const float4* src = (const float4*)(xc + h0 * W);
        float4* dst = (float4*)(oc + h0 * W);
        dst[threadIdx.x] = src[threadIdx.x];
        return;
    }

    // Laplace path: stage rows h0-1 .. h0+8 (10 rows) with zero padding
    __shared__ float tile[ROWS + 2][W];
    for (int i = threadIdx.x; i < (ROWS + 2) * (W / 4); i += 256) {
        int r = i / (W / 4);
        int cvec = i % (W / 4);
        int h = h0 - 1 + r;
        float4 v = make_float4(0.f, 0.f, 0.f, 0.f);
        if (h >= 0 && h < H) v = ((const float4*)(xc + h * W))[cvec];
        ((float4*)tile[r])[cvec] = v;
    }
    __syncthreads();

    for (int i = threadIdx.x; i < ROWS * W; i += 256) {
        int r = i >> 7;          // / W
        int col = i & (W - 1);   // % W
        int tr = r + 1;
        float cc = tile[tr][col];
        float up = tile[tr - 1][col];
        float dn = tile[tr + 1][col];
        float lf = 0.f, rt = 0.f, ul = 0.f, ur = 0.f, dl = 0.f, dr = 0.f;
        if (col > 0) {
            lf = tile[tr][col - 1];
            ul = tile[tr - 1][col - 1];
            dl = tile[tr + 1][col - 1];
        }
        if (col < W - 1) {
            rt = tile[tr][col + 1];
            ur = tile[tr - 1][col + 1];
            dr = tile[tr + 1][col + 1];
        }
        float res = 8.0f * cc - (up + dn + lf + rt + ul + ur + dl + dr);
        oc[(h0 + r) * W + col] = res;
    }
}

extern "C" void kernel_launch(void* const* d_in, const int* in_sizes, int n_in,
                              void* d_out, int out_size, void* d_ws, size_t ws_size,
                              hipStream_t stream) {
    const float* x = (const float*)d_in[0];
    float* out = (float*)d_out;

    double* scores = (double*)d_ws;                       // 4096 doubles
    unsigned char* sel = (unsigned char*)(scores + BC);   // 4096 bytes

    score_kernel<<<BC, 256, 0, stream>>>(x, scores);
    select_kernel<<<B, 256, 0, stream>>>(scores, sel);
    apply_kernel<<<BC * (H / ROWS), 256, 0, stream>>>(x, sel, out);
}

// Round 3
// 182.310 us; speedup vs baseline: 1.0703x; 1.0703x over previous
//
#include <hip/hip_runtime.h>
#include <hip/hip_bf16.h>

// Problem constants: x is [16, 256, 128, 128] float32.
#define B 16
#define C 256
#define H 128
#define W 128
#define HW (H * W)            // 16384
#define BC (B * C)            // 4096
#define KSEL 26               // round(0.1 * 256)

// native 16B vector type (works with __builtin_nontemporal_store)
typedef float v4f __attribute__((ext_vector_type(4)));

// -------------------- Kernel 1: per-channel score --------------------
// One block (256 threads) per (b,c). 16 float4 per thread.
// Histogram packed into two u64 accumulators with 8-bit fields (per-thread
// count per bin <= 64, fits). Sum/sumsq accumulated f32-per-float4, folded
// into double once per iteration (f64 ops out of the hot path).
__global__ __launch_bounds__(256) void score_kernel(const float* __restrict__ x,
                                                    double* __restrict__ score) {
    const int bc = blockIdx.x;
    const v4f* xv = (const v4f*)(x + (size_t)bc * HW);

    unsigned long long acc0 = 0ULL, acc1 = 0ULL;  // bins 0..7 / 8..10
    double sum = 0.0, sumsq = 0.0;

    for (int i = threadIdx.x; i < HW / 4; i += 256) {
        v4f v = xv[i];
        float s4 = (v.x + v.y) + (v.z + v.w);
        float q4 = fmaf(v.w, v.w, fmaf(v.z, v.z, fmaf(v.y, v.y, v.x * v.x)));
        sum += (double)s4;
        sumsq += (double)q4;
        float arr[4] = {v.x, v.y, v.z, v.w};
#pragma unroll
        for (int j = 0; j < 4; ++j) {
            float f = arr[j];
            // numpy float32 pipeline: round-half-even of tanh(x)*10
            float qf = rintf(tanhf(f) * 10.0f);
            int bin = (int)qf;
            bool ok = (qf >= 0.0f) && (qf <= 10.0f);
            unsigned long long one = 1ULL << ((bin & 7) * 8);
            acc0 += (ok && bin < 8) ? one : 0ULL;
            acc1 += (ok && bin >= 8) ? one : 0ULL;
        }
    }

    // unpack 8-bit fields -> 11 ints (epilogue only)
    int cnt[11];
#pragma unroll
    for (int k = 0; k < 8; ++k) cnt[k] = (int)((acc0 >> (k * 8)) & 0xFF);
#pragma unroll
    for (int k = 8; k < 11; ++k) cnt[k] = (int)((acc1 >> ((k - 8) * 8)) & 0xFF);

    // wave(64)-level reduction
#pragma unroll
    for (int off = 32; off > 0; off >>= 1) {
#pragma unroll
        for (int k = 0; k < 11; ++k) cnt[k] += __shfl_down(cnt[k], off);
        sum += __shfl_down(sum, off);
        sumsq += __shfl_down(sumsq, off);
    }

    __shared__ int sh_cnt[4][11];
    __shared__ double sh_sum[4], sh_sq[4];
    const int wave = threadIdx.x >> 6;
    const int lane = threadIdx.x & 63;
    if (lane == 0) {
#pragma unroll
        for (int k = 0; k < 11; ++k) sh_cnt[wave][k] = cnt[k];
        sh_sum[wave] = sum;
        sh_sq[wave] = sumsq;
    }
    __syncthreads();

    if (threadIdx.x == 0) {
        int c[11];
        int tot = 0;
#pragma unroll
        for (int k = 0; k < 11; ++k) {
            c[k] = sh_cnt[0][k] + sh_cnt[1][k] + sh_cnt[2][k] + sh_cnt[3][k];
            tot += c[k];
        }
        double s = sh_sum[0] + sh_sum[1] + sh_sum[2] + sh_sum[3];
        double sq = sh_sq[0] + sh_sq[1] + sh_sq[2] + sh_sq[3];

        double ent = 0.0;
        double inv = 1.0 / (double)tot;
#pragma unroll
        for (int k = 0; k < 11; ++k) {
            double p = (double)c[k] * inv;
            if (p > 0.0) ent -= p * log(p);
        }
        const double L = (double)HW;
        double var = (sq - s * s / L) / (L - 1.0);
        score[bc] = ent + 2.0 / (var + 1e-7);
    }
}

// -------------------- Kernel 2: top-k selection per batch --------------------
// One block per batch; rank-by-counting with stable-argsort tie semantics.
__global__ __launch_bounds__(256) void select_kernel(const double* __restrict__ score,
                                                     unsigned char* __restrict__ sel) {
    __shared__ double s[C];
    const int b = blockIdx.x;
    const int t = threadIdx.x;
    s[t] = score[b * C + t];
    __syncthreads();
    const double mine = s[t];
    int rank = 0;
    for (int j = 0; j < C; ++j) {
        double v = s[j];
        rank += (v > mine) || (v == mine && j < t);
    }
    sel[b * C + t] = (rank < KSEL) ? 1 : 0;
}

// -------------------- Kernel 3: apply Laplace or copy --------------------
// One block (256 threads) per channel. Uniform branch on sel.
#define ROWS 8
__global__ __launch_bounds__(256) void apply_kernel(const float* __restrict__ x,
                                                    const unsigned char* __restrict__ sel,
                                                    float* __restrict__ out) {
    const int bc = blockIdx.x;
    const float* xc = x + (size_t)bc * HW;
    float* oc = out + (size_t)bc * HW;

    if (!sel[bc]) {
        // pure copy: 4096 float4 per channel, 16 per thread; nontemporal store
        const v4f* src = (const v4f*)xc;
        v4f* dst = (v4f*)oc;
#pragma unroll
        for (int i = 0; i < 16; ++i) {
            v4f v = src[threadIdx.x + i * 256];
            __builtin_nontemporal_store(v, &dst[threadIdx.x + i * 256]);
        }
        return;
    }

    // Laplace path: 16 chunks of 8 rows; stage rows h0-1 .. h0+8 with zero pad
    __shared__ float tile[ROWS + 2][W];
    for (int chunk = 0; chunk < H / ROWS; ++chunk) {
        const int h0 = chunk * ROWS;
        for (int i = threadIdx.x; i < (ROWS + 2) * (W / 4); i += 256) {
            int r = i >> 5;        // / (W/4)
            int cvec = i & 31;     // % (W/4)
            int h = h0 - 1 + r;
            v4f v = (v4f)(0.f);
            if (h >= 0 && h < H) v = ((const v4f*)(xc + h * W))[cvec];
            ((v4f*)tile[r])[cvec] = v;
        }
        __syncthreads();

        for (int i = threadIdx.x; i < ROWS * W; i += 256) {
            int r = i >> 7;          // / W
            int col = i & (W - 1);   // % W
            int tr = r + 1;
            float cc = tile[tr][col];
            float up = tile[tr - 1][col];
            float dn = tile[tr + 1][col];
            float lf = 0.f, rt = 0.f, ul = 0.f, ur = 0.f, dl = 0.f, dr = 0.f;
            if (col > 0) {
                lf = tile[tr][col - 1];
                ul = tile[tr - 1][col - 1];
                dl = tile[tr + 1][col - 1];
            }
            if (col < W - 1) {
                rt = tile[tr][col + 1];
                ur = tile[tr - 1][col + 1];
                dr = tile[tr + 1][col + 1];
            }
            float res = 8.0f * cc - (up + dn + lf + rt + ul + ur + dl + dr);
            __builtin_nontemporal_store(res, &oc[(h0 + r) * W + col]);
        }
        __syncthreads();
    }
}

extern "C" void kernel_launch(void* const* d_in, const int* in_sizes, int n_in,
                              void* d_out, int out_size, void* d_ws, size_t ws_size,
                              hipStream_t stream) {
    const float* x = (const float*)d_in[0];
    float* out = (float*)d_out;

    double* scores = (double*)d_ws;                       // 4096 doubles
    unsigned char* sel = (unsigned char*)(scores + BC);   // 4096 bytes

    score_kernel<<<BC, 256, 0, stream>>>(x, scores);
    select_kernel<<<B, 256, 0, stream>>>(scores, sel);
    apply_kernel<<<BC, 256, 0, stream>>>(x, sel, out);
}

// Round 4
// 175.338 us; speedup vs baseline: 1.1129x; 1.0398x over previous
//
#include <hip/hip_runtime.h>
#include <hip/hip_bf16.h>

// Problem constants: x is [16, 256, 128, 128] float32.
#define B 16
#define C 256
#define H 128
#define W 128
#define HW (H * W)            // 16384
#define BC (B * C)            // 4096
#define KSEL 26               // round(0.1 * 256)

typedef float v4f __attribute__((ext_vector_type(4)));

// ordered-int mapping for monotone binary search over float bits
__device__ __forceinline__ unsigned ordf(float x) {
    unsigned u = __float_as_uint(x);
    return (u & 0x80000000u) ? ~u : (u | 0x80000000u);
}
__device__ __forceinline__ float unordf(unsigned k) {
    unsigned u = (k & 0x80000000u) ? (k & 0x7fffffffu) : ~k;
    return __uint_as_float(u);
}

// -------------------- Kernel 0: derive exact bin thresholds --------------------
// thr[k] = smallest float x in [-2,4] with rintf(tanhf(x)*10.f) >= k, k=0..10.
// Uses the device's own tanhf/rintf -> binning via compares is bit-identical
// to the direct evaluation (tanhf monotone).
__global__ void init_thresholds(float* __restrict__ thr) {
    int k = threadIdx.x;
    if (k > 10) return;
    unsigned lo = ordf(-2.0f), hi = ordf(4.0f);  // f(-2)=-10<k<=f(4)=10
    while (lo < hi) {
        unsigned mid = lo + (hi - lo) / 2;
        float xm = unordf(mid);
        float q = rintf(tanhf(xm) * 10.0f);
        if (q >= (float)k) hi = mid; else lo = mid + 1;
    }
    thr[k] = unordf(lo);
}

// -------------------- Kernel 1: per-channel score --------------------
// One block (256 threads) per (b,c). 16 float4 per thread.
// Histogram via ballot+popcount: cge[k] = #{x >= thr[k]}, wave-uniform.
// Per wave-iteration (256 elems): 44 v_cmp + ~9 VALU -> memory-bound.
__global__ __launch_bounds__(256) void score_kernel(const float* __restrict__ x,
                                                    const float* __restrict__ thr,
                                                    double* __restrict__ score) {
    const int bc = blockIdx.x;
    const v4f* xv = (const v4f*)(x + (size_t)bc * HW);

    float t[11];
#pragma unroll
    for (int k = 0; k < 11; ++k) t[k] = thr[k];

    unsigned cge[11];
#pragma unroll
    for (int k = 0; k < 11; ++k) cge[k] = 0;
    double sum = 0.0, sumsq = 0.0;

    for (int i = threadIdx.x; i < HW / 4; i += 256) {
        v4f v = xv[i];
        float s4 = (v.x + v.y) + (v.z + v.w);
        float q4 = fmaf(v.w, v.w, fmaf(v.z, v.z, fmaf(v.y, v.y, v.x * v.x)));
        sum += (double)s4;
        sumsq += (double)q4;
        float arr[4] = {v.x, v.y, v.z, v.w};
#pragma unroll
        for (int j = 0; j < 4; ++j) {
            float f = arr[j];
#pragma unroll
            for (int k = 0; k < 11; ++k)
                cge[k] += (unsigned)__popcll(__ballot(f >= t[k]));
        }
    }

    // cge[] already wave-level (uniform). Reduce sum/sumsq across the wave.
#pragma unroll
    for (int off = 32; off > 0; off >>= 1) {
        sum += __shfl_down(sum, off);
        sumsq += __shfl_down(sumsq, off);
    }

    __shared__ unsigned sh_cge[4][11];
    __shared__ double sh_sum[4], sh_sq[4];
    const int wave = threadIdx.x >> 6;
    const int lane = threadIdx.x & 63;
    if (lane == 0) {
#pragma unroll
        for (int k = 0; k < 11; ++k) sh_cge[wave][k] = cge[k];
        sh_sum[wave] = sum;
        sh_sq[wave] = sumsq;
    }
    __syncthreads();

    if (threadIdx.x == 0) {
        unsigned g[11];
#pragma unroll
        for (int k = 0; k < 11; ++k)
            g[k] = sh_cge[0][k] + sh_cge[1][k] + sh_cge[2][k] + sh_cge[3][k];
        // bin counts: c[k] = g[k] - g[k+1], c[10] = g[10]; tot = g[0]
        double s = sh_sum[0] + sh_sum[1] + sh_sum[2] + sh_sum[3];
        double sq = sh_sq[0] + sh_sq[1] + sh_sq[2] + sh_sq[3];

        double ent = 0.0;
        double inv = 1.0 / (double)g[0];
#pragma unroll
        for (int k = 0; k < 11; ++k) {
            unsigned ck = (k < 10) ? (g[k] - g[k + 1]) : g[10];
            double p = (double)ck * inv;
            if (p > 0.0) ent -= p * log(p);
        }
        const double L = (double)HW;
        double var = (sq - s * s / L) / (L - 1.0);
        score[bc] = ent + 2.0 / (var + 1e-7);
    }
}

// -------------------- Kernel 2: top-k selection per batch --------------------
// One block per batch; rank-by-counting with stable-argsort tie semantics.
__global__ __launch_bounds__(256) void select_kernel(const double* __restrict__ score,
                                                     unsigned char* __restrict__ sel) {
    __shared__ double s[C];
    const int b = blockIdx.x;
    const int t = threadIdx.x;
    s[t] = score[b * C + t];
    __syncthreads();
    const double mine = s[t];
    int rank = 0;
    for (int j = 0; j < C; ++j) {
        double v = s[j];
        rank += (v > mine) || (v == mine && j < t);
    }
    sel[b * C + t] = (rank < KSEL) ? 1 : 0;
}

// -------------------- Kernel 3: apply Laplace or copy --------------------
// One block (256 threads) per channel. Uniform branch on sel.
#define ROWS 8
__global__ __launch_bounds__(256) void apply_kernel(const float* __restrict__ x,
                                                    const unsigned char* __restrict__ sel,
                                                    float* __restrict__ out) {
    const int bc = blockIdx.x;
    const float* xc = x + (size_t)bc * HW;
    float* oc = out + (size_t)bc * HW;

    if (!sel[bc]) {
        // pure copy: 4096 float4 per channel, 16 per thread; nontemporal store
        const v4f* src = (const v4f*)xc;
        v4f* dst = (v4f*)oc;
#pragma unroll
        for (int i = 0; i < 16; ++i) {
            v4f v = src[threadIdx.x + i * 256];
            __builtin_nontemporal_store(v, &dst[threadIdx.x + i * 256]);
        }
        return;
    }

    // Laplace path: 16 chunks of 8 rows; stage rows h0-1 .. h0+8 with zero pad
    __shared__ float tile[ROWS + 2][W];
    for (int chunk = 0; chunk < H / ROWS; ++chunk) {
        const int h0 = chunk * ROWS;
        for (int i = threadIdx.x; i < (ROWS + 2) * (W / 4); i += 256) {
            int r = i >> 5;        // / (W/4)
            int cvec = i & 31;     // % (W/4)
            int h = h0 - 1 + r;
            v4f v = (v4f)(0.f);
            if (h >= 0 && h < H) v = ((const v4f*)(xc + h * W))[cvec];
            ((v4f*)tile[r])[cvec] = v;
        }
        __syncthreads();

        for (int i = threadIdx.x; i < ROWS * W; i += 256) {
            int r = i >> 7;          // / W
            int col = i & (W - 1);   // % W
            int tr = r + 1;
            float cc = tile[tr][col];
            float up = tile[tr - 1][col];
            float dn = tile[tr + 1][col];
            float lf = 0.f, rt = 0.f, ul = 0.f, ur = 0.f, dl = 0.f, dr = 0.f;
            if (col > 0) {
                lf = tile[tr][col - 1];
                ul = tile[tr - 1][col - 1];
                dl = tile[tr + 1][col - 1];
            }
            if (col < W - 1) {
                rt = tile[tr][col + 1];
                ur = tile[tr - 1][col + 1];
                dr = tile[tr + 1][col + 1];
            }
            float res = 8.0f * cc - (up + dn + lf + rt + ul + ur + dl + dr);
            __builtin_nontemporal_store(res, &oc[(h0 + r) * W + col]);
        }
        __syncthreads();
    }
}

extern "C" void kernel_launch(void* const* d_in, const int* in_sizes, int n_in,
                              void* d_out, int out_size, void* d_ws, size_t ws_size,
                              hipStream_t stream) {
    const float* x = (const float*)d_in[0];
    float* out = (float*)d_out;

    double* scores = (double*)d_ws;                         // 4096 doubles
    unsigned char* sel = (unsigned char*)(scores + BC);     // 4096 bytes
    float* thr = (float*)(sel + BC);                        // 11 floats

    init_thresholds<<<1, 64, 0, stream>>>(thr);
    score_kernel<<<BC, 256, 0, stream>>>(x, thr, scores);
    select_kernel<<<B, 256, 0, stream>>>(scores, sel);
    apply_kernel<<<BC, 256, 0, stream>>>(x, sel, out);
}

// Round 5
// 117.705 us; speedup vs baseline: 1.6578x; 1.4896x over previous
//
#include <hip/hip_runtime.h>
#include <hip/hip_bf16.h>

// Problem constants: x is [16, 256, 128, 128] float32.
#define B 16
#define C 256
#define H 128
#define W 128
#define HW (H * W)            // 16384
#define BC (B * C)            // 4096
#define KSEL 26               // round(0.1 * 256)

typedef float v4f __attribute__((ext_vector_type(4)));

// ordered-int mapping for monotone binary search over float bits
__device__ __forceinline__ unsigned ordf(float x) {
    unsigned u = __float_as_uint(x);
    return (u & 0x80000000u) ? ~u : (u | 0x80000000u);
}
__device__ __forceinline__ float unordf(unsigned k) {
    unsigned u = (k & 0x80000000u) ? (k & 0x7fffffffu) : ~k;
    return __uint_as_float(u);
}

// -------------------- Kernel 0: derive exact bin thresholds --------------------
// thr[k] = smallest float x in [-2,4] with rintf(tanhf(x)*10.f) >= k, k=0..10.
// Device's own tanhf/rintf -> compare-based binning is bit-identical (monotone).
__global__ void init_thresholds(float* __restrict__ thr) {
    int k = threadIdx.x;
    if (k > 10) return;
    unsigned lo = ordf(-2.0f), hi = ordf(4.0f);
    while (lo < hi) {
        unsigned mid = lo + (hi - lo) / 2;
        float xm = unordf(mid);
        float q = rintf(tanhf(xm) * 10.0f);
        if (q >= (float)k) hi = mid; else lo = mid + 1;
    }
    thr[k] = unordf(lo);
}

// -------------------- Kernel 1: fused per-channel score + copy --------------------
// One block (256 threads) per (b,c). 16 float4 per thread.
// While streaming x, also write out = x (nontemporal). 90% of channels need
// nothing else; selected ones are overwritten by laplace_kernel.
__global__ __launch_bounds__(256) void score_copy_kernel(const float* __restrict__ x,
                                                         const float* __restrict__ thr,
                                                         double* __restrict__ score,
                                                         float* __restrict__ out) {
    const int bc = blockIdx.x;
    const v4f* xv = (const v4f*)(x + (size_t)bc * HW);
    v4f* ov = (v4f*)(out + (size_t)bc * HW);

    float t[11];
#pragma unroll
    for (int k = 0; k < 11; ++k) t[k] = thr[k];

    unsigned cge[11];
#pragma unroll
    for (int k = 0; k < 11; ++k) cge[k] = 0;
    double sum = 0.0, sumsq = 0.0;

    for (int i = threadIdx.x; i < HW / 4; i += 256) {
        v4f v = xv[i];
        __builtin_nontemporal_store(v, &ov[i]);
        float s4 = (v.x + v.y) + (v.z + v.w);
        float q4 = fmaf(v.w, v.w, fmaf(v.z, v.z, fmaf(v.y, v.y, v.x * v.x)));
        sum += (double)s4;
        sumsq += (double)q4;
        float arr[4] = {v.x, v.y, v.z, v.w};
#pragma unroll
        for (int j = 0; j < 4; ++j) {
            float f = arr[j];
#pragma unroll
            for (int k = 0; k < 11; ++k)
                cge[k] += (unsigned)__popcll(__ballot(f >= t[k]));
        }
    }

    // cge[] is wave-uniform. Reduce sum/sumsq across the wave.
#pragma unroll
    for (int off = 32; off > 0; off >>= 1) {
        sum += __shfl_down(sum, off);
        sumsq += __shfl_down(sumsq, off);
    }

    __shared__ unsigned sh_cge[4][11];
    __shared__ double sh_sum[4], sh_sq[4];
    const int wave = threadIdx.x >> 6;
    const int lane = threadIdx.x & 63;
    if (lane == 0) {
#pragma unroll
        for (int k = 0; k < 11; ++k) sh_cge[wave][k] = cge[k];
        sh_sum[wave] = sum;
        sh_sq[wave] = sumsq;
    }
    __syncthreads();

    if (threadIdx.x == 0) {
        unsigned g[11];
#pragma unroll
        for (int k = 0; k < 11; ++k)
            g[k] = sh_cge[0][k] + sh_cge[1][k] + sh_cge[2][k] + sh_cge[3][k];
        double s = sh_sum[0] + sh_sum[1] + sh_sum[2] + sh_sum[3];
        double sq = sh_sq[0] + sh_sq[1] + sh_sq[2] + sh_sq[3];

        double ent = 0.0;
        double inv = 1.0 / (double)g[0];
#pragma unroll
        for (int k = 0; k < 11; ++k) {
            unsigned ck = (k < 10) ? (g[k] - g[k + 1]) : g[10];
            double p = (double)ck * inv;
            if (p > 0.0) ent -= p * log(p);
        }
        const double L = (double)HW;
        double var = (sq - s * s / L) / (L - 1.0);
        score[bc] = ent + 2.0 / (var + 1e-7);
    }
}

// -------------------- Kernel 2: top-k selection -> compact index list --------------------
// One block per batch; rank-by-counting with stable-argsort tie semantics.
// rank < KSEL is unique per selected channel -> compact slot.
__global__ __launch_bounds__(256) void select_kernel(const double* __restrict__ score,
                                                     int* __restrict__ compact) {
    __shared__ double s[C];
    const int b = blockIdx.x;
    const int t = threadIdx.x;
    s[t] = score[b * C + t];
    __syncthreads();
    const double mine = s[t];
    int rank = 0;
    for (int j = 0; j < C; ++j) {
        double v = s[j];
        rank += (v > mine) || (v == mine && j < t);
    }
    if (rank < KSEL) compact[b * KSEL + rank] = t;
}

// -------------------- Kernel 3: Laplace rewrite of selected channels --------------------
// Exactly B*KSEL channels; 8 blocks per channel (16 rows each), one barrier.
#define LROWS 16
#define PERCH (H / LROWS)   // 8
__global__ __launch_bounds__(256) void laplace_kernel(const float* __restrict__ x,
                                                      const int* __restrict__ compact,
                                                      float* __restrict__ out) {
    const int blk = blockIdx.x;
    const int b = blk / (KSEL * PERCH);
    const int r0 = blk % (KSEL * PERCH);
    const int slot = r0 / PERCH;
    const int chunk = r0 % PERCH;
    const int c = compact[b * KSEL + slot];
    const size_t base = (size_t)(b * C + c) * HW;
    const float* xc = x + base;
    float* oc = out + base;
    const int h0 = chunk * LROWS;

    __shared__ float tile[LROWS + 2][W];
    for (int i = threadIdx.x; i < (LROWS + 2) * (W / 4); i += 256) {
        int rr = i >> 5;       // / (W/4)
        int cv = i & 31;       // % (W/4)
        int h = h0 - 1 + rr;
        v4f v = (v4f)(0.f);
        if (h >= 0 && h < H) v = ((const v4f*)(xc + h * W))[cv];
        ((v4f*)tile[rr])[cv] = v;
    }
    __syncthreads();

    for (int i = threadIdx.x; i < LROWS * W; i += 256) {
        int rr = i >> 7;          // / W
        int col = i & (W - 1);    // % W
        int tr = rr + 1;
        float cc = tile[tr][col];
        float up = tile[tr - 1][col];
        float dn = tile[tr + 1][col];
        float lf = 0.f, rt = 0.f, ul = 0.f, ur = 0.f, dl = 0.f, dr = 0.f;
        if (col > 0) {
            lf = tile[tr][col - 1];
            ul = tile[tr - 1][col - 1];
            dl = tile[tr + 1][col - 1];
        }
        if (col < W - 1) {
            rt = tile[tr][col + 1];
            ur = tile[tr - 1][col + 1];
            dr = tile[tr + 1][col + 1];
        }
        float res = 8.0f * cc - (up + dn + lf + rt + ul + ur + dl + dr);
        __builtin_nontemporal_store(res, &oc[(h0 + rr) * W + col]);
    }
}

extern "C" void kernel_launch(void* const* d_in, const int* in_sizes, int n_in,
                              void* d_out, int out_size, void* d_ws, size_t ws_size,
                              hipStream_t stream) {
    const float* x = (const float*)d_in[0];
    float* out = (float*)d_out;

    double* scores = (double*)d_ws;                         // 4096 doubles
    int* compact = (int*)(scores + BC);                     // 416 ints
    float* thr = (float*)(compact + B * KSEL);              // 11 floats

    init_thresholds<<<1, 64, 0, stream>>>(thr);
    score_copy_kernel<<<BC, 256, 0, stream>>>(x, thr, scores, out);
    select_kernel<<<B, 256, 0, stream>>>(scores, compact);
    laplace_kernel<<<B * KSEL * PERCH, 256, 0, stream>>>(x, compact, out);
}